// Round 6
// baseline (208.865 us; speedup 1.0000x reference)
//
#include <hip/hip_runtime.h>

#define N_NODES 100000
#define N_EDGES 1600000
#define D_IN    128
#define D_OUT   64

// Bucket scheme: nodes grouped into buckets of G; per-bucket edge lists with
// fixed capacity CAP (avg fill 3840, binomial sd ~62 -> 6144 is ~37 sigma).
#define G     240
#define NBKT  ((N_NODES + G - 1) / G)          // 417
#define CAP   6144
#define EPB   8192                              // edges per partition block
#define PBLK  ((N_EDGES + EPB - 1) / EPB)       // 196
#define GBLK  ((N_NODES + 127) / 128)           // 782 gemm blocks (128 nodes ea)

// hb layout: 4 feature-plane SoA slices. hb[p][node][16 feats bf16];
// plane = 3.2 MB -> per-XCD L2-resident when plane s is pinned to XCDs
// {s, s+4} via blk = b*4+s (verified R5: FETCH 77 -> 40 MB).
#define NPLANE 4
#define PLANE_STRIDE ((size_t)N_NODES * 16)     // ushorts per plane

// Wt LDS row stride (shorts): 136 = 4 mod 32 banks -> conflict-minimal b128
#define WSTR  136

typedef __attribute__((ext_vector_type(8))) short bf16x8;
typedef __attribute__((ext_vector_type(4))) float f32x4;
typedef __attribute__((ext_vector_type(8))) unsigned short us16x8;

// fp32 <-> bf16 helpers (RNE)
__device__ __forceinline__ unsigned short f2bf(float f) {
    union { float f; unsigned u; } v; v.f = f;
    const unsigned r = v.u + 0x7FFFu + ((v.u >> 16) & 1u);
    return (unsigned short)(r >> 16);
}
__device__ __forceinline__ float bf2f(unsigned short s) {
    union { unsigned u; float f; } v; v.u = ((unsigned)s) << 16;
    return v.f;
}
__device__ __forceinline__ unsigned cvt_pk_bf16(float lo, float hi) {
    unsigned r;
    asm volatile("v_cvt_pk_bf16_f32 %0, %1, %2" : "=v"(r) : "v"(lo), "v"(hi));
    return r;
}

// DIAGNOSTIC pad (~20us, accumulate only): lifts it above the 41us ws-poison
// fills so dur/FETCH/WRITE surface in the top-5 table.
__device__ __forceinline__ void spin_pad_20us() {
    const unsigned long long t0 = __builtin_amdgcn_s_memrealtime();
    for (int i = 0; i < 2000000; ++i) {
        if (__builtin_amdgcn_s_memrealtime() - t0 >= 2000ULL) break;
    }
}

// ---------------------------------------------------------------------------
// Fused gemm + partition (unchanged from R5; real ~25us measured R1/R4).
// ---------------------------------------------------------------------------
__global__ __launch_bounds__(512) void fused_gp_kernel(const float* __restrict__ x,
                                                       const float* __restrict__ W,
                                                       unsigned short* __restrict__ hb,
                                                       const int* __restrict__ ei,
                                                       int* __restrict__ gcur,
                                                       int* __restrict__ ebuf) {
    __shared__ int smem[1536 + EPB + EPB / 2];   // 55296 B

    const int tid = threadIdx.x;

    if (blockIdx.x < PBLK) {
        // ----------------- partition path -----------------------------------
        int* cnt   = smem;            // [512]
        int* sA    = smem + 512;      // [512] inclusive scan
        int* gbase = smem + 1024;     // [512] adjusted global base (first 8: wave sums)
        int* stage = smem + 1536;     // [EPB] packed edges, bucket-grouped
        unsigned short* bstage = (unsigned short*)(smem + 1536 + EPB); // [EPB]

        cnt[tid] = 0;
        __syncthreads();

        const int e0   = blockIdx.x * EPB;
        const int ecnt = min(EPB, N_EDGES - e0);

        int pk[16], meta[16];
        #pragma unroll
        for (int i = 0; i < 16; ++i) {
            const int l = tid + i * 512;
            meta[i] = -1;
            if (l < ecnt) {
                const int e   = e0 + l;
                const int src = ei[e];
                const int dst = ei[N_EDGES + e];
                const int b   = dst / G;
                const int dl  = dst - b * G;
                pk[i] = src | (dl << 17);
                const int r = atomicAdd(&cnt[b], 1);   // LDS atomic
                meta[i] = b | (r << 9);                // b:9b, r<8192:13b
            }
        }
        __syncthreads();

        // wave-level inclusive scan of cnt[0..511] (2 barriers)
        {
            const int wv = tid >> 6, ln = tid & 63;
            int s = cnt[tid];
            #pragma unroll
            for (int off = 1; off < 64; off <<= 1) {
                const int t = __shfl_up(s, off, 64);
                if (ln >= off) s += t;
            }
            if (ln == 63) gbase[wv] = s;        // wave totals (gbase[0..7] temp)
            __syncthreads();
            int wbase = 0;
            #pragma unroll
            for (int w = 0; w < 8; ++w) wbase += (w < wv) ? gbase[w] : 0;
            sA[tid] = s + wbase;
            __syncthreads();
        }

        if (tid < NBKT) {
            const int c  = cnt[tid];
            const int ex = sA[tid] - c;
            if (c > 0) gbase[tid] = atomicAdd(&gcur[tid], c) - ex;
        }
        __syncthreads();

        #pragma unroll
        for (int i = 0; i < 16; ++i) {
            if (meta[i] >= 0) {
                const int b    = meta[i] & 511;
                const int r    = meta[i] >> 9;
                const int spos = (sA[b] - cnt[b]) + r;
                stage[spos]  = pk[i];
                bstage[spos] = (unsigned short)b;
            }
        }
        __syncthreads();

        #pragma unroll
        for (int i = 0; i < 16; ++i) {
            const int idx = tid + i * 512;
            if (idx < ecnt) {
                const int b   = bstage[idx];
                const int pib = gbase[b] + idx;     // position in bucket
                if ((unsigned)pib < CAP) ebuf[b * CAP + pib] = stage[idx];
            }
        }
    } else {
        // ----------------- gemm path (bf16 MFMA, padded W^T in LDS) ---------
        unsigned short* Wt = reinterpret_cast<unsigned short*>(smem);
        for (int i = tid; i < (D_IN / 2) * D_OUT; i += 512) {
            const int f  = i & 63;
            const int k2 = (i >> 6) * 2;
            const float w0 = W[k2 * 64 + f];
            const float w1 = W[(k2 + 1) * 64 + f];
            *reinterpret_cast<unsigned*>(&Wt[f * WSTR + k2]) = cvt_pk_bf16(w0, w1);
        }
        __syncthreads();

        const int wave = tid >> 6;                     // 0..7
        const int lane = tid & 63;
        const int m    = lane & 15;
        const int quad = lane >> 4;
        const int n0   = (blockIdx.x - PBLK) * 128 + wave * 16;

        bf16x8 bfrag[4][4];
        #pragma unroll
        for (int ft = 0; ft < 4; ++ft)
            #pragma unroll
            for (int ks = 0; ks < 4; ++ks)
                bfrag[ft][ks] = *reinterpret_cast<const bf16x8*>(
                    &Wt[(ft * 16 + m) * WSTR + ks * 32 + quad * 8]);

        const int nodeA = min(n0 + m, N_NODES - 1);
        const float* xr = x + (size_t)nodeA * D_IN;
        bf16x8 afrag[4];
        #pragma unroll
        for (int ks = 0; ks < 4; ++ks) {
            const float4 u = *reinterpret_cast<const float4*>(xr + ks * 32 + quad * 8);
            const float4 v = *reinterpret_cast<const float4*>(xr + ks * 32 + quad * 8 + 4);
            union { unsigned u32[4]; bf16x8 v8; } c;
            c.u32[0] = cvt_pk_bf16(u.x, u.y);
            c.u32[1] = cvt_pk_bf16(u.z, u.w);
            c.u32[2] = cvt_pk_bf16(v.x, v.y);
            c.u32[3] = cvt_pk_bf16(v.z, v.w);
            afrag[ks] = c.v8;
        }

        f32x4 acc[4];
        #pragma unroll
        for (int ft = 0; ft < 4; ++ft) { acc[ft][0]=0.f; acc[ft][1]=0.f; acc[ft][2]=0.f; acc[ft][3]=0.f; }

        #pragma unroll
        for (int ks = 0; ks < 4; ++ks)
            #pragma unroll
            for (int ft = 0; ft < 4; ++ft)
                acc[ft] = __builtin_amdgcn_mfma_f32_16x16x32_bf16(
                    afrag[ks], bfrag[ft][ks], acc[ft], 0, 0, 0);

        // plane-layout epilogue: feature ft*16+m -> plane ft, pos m.
        #pragma unroll
        for (int r = 0; r < 4; ++r) {
            const int node = n0 + quad * 4 + r;
            if (node < N_NODES) {
                #pragma unroll
                for (int ft = 0; ft < 4; ++ft)
                    hb[ft * PLANE_STRIDE + (size_t)node * 16 + m] = f2bf(acc[ft][r]);
            }
        }
    }
}

// ---------------------------------------------------------------------------
// CSR build (NEW round 6): ONCE per bucket (was 4x inside accumulate -- R5
// counters: VALUBusy 31%, 1.98M bank conflicts, real time UP ~10us).
// Reads ebuf, builds row-sorted edge list + offsets, writes to global.
// Scatter goes straight to global (24KB window/bucket, L2-buffered).
// ---------------------------------------------------------------------------
__global__ __launch_bounds__(512) void csr_kernel(const int* __restrict__ gcur,
                                                  const int* __restrict__ ebuf,
                                                  int* __restrict__ gsrt,
                                                  int* __restrict__ gstart) {
    __shared__ int cnt[256];
    __shared__ int start[G + 1];

    const int b   = blockIdx.x;
    const int tid = threadIdx.x;
    const int ecnt = min(gcur[b], CAP);

    if (tid < 256) cnt[tid] = 0;
    __syncthreads();

    int pk[12], rr[12];
    #pragma unroll
    for (int i = 0; i < 12; ++i) {               // 12*512 = 6144 = CAP
        const int idx = tid + i * 512;
        rr[i] = -1;
        if (idx < ecnt) {
            pk[i] = ebuf[(size_t)b * CAP + idx];
            rr[i] = atomicAdd(&cnt[pk[i] >> 17], 1);
        }
    }
    __syncthreads();

    // single-wave exclusive scan of cnt[0..239] -> start[0..240]
    if (tid < 64) {
        int v[4]; int sum = 0;
        #pragma unroll
        for (int k = 0; k < 4; ++k) {
            const int idx = tid * 4 + k;
            v[k] = (idx < G) ? cnt[idx] : 0;
            sum += v[k];
        }
        const int mine = sum;
        for (int off = 1; off < 64; off <<= 1) {
            const int t = __shfl_up(sum, off, 64);
            if (tid >= off) sum += t;
        }
        int base = sum - mine;
        #pragma unroll
        for (int k = 0; k < 4; ++k) {
            const int idx = tid * 4 + k;
            if (idx <= G) start[idx] = base;
            base += v[k];
        }
        if (tid == 63) start[G] = base;
    }
    __syncthreads();

    #pragma unroll
    for (int i = 0; i < 12; ++i) {
        if (rr[i] >= 0) {
            const int dl = pk[i] >> 17;
            gsrt[(size_t)b * CAP + start[dl] + rr[i]] = pk[i] & 0x1FFFF;
        }
    }
    if (tid <= G) gstart[b * 256 + tid] = start[tid];
}

// ---------------------------------------------------------------------------
// Accumulate v9: pure gather. slice s = blk&3 keeps the R5 plane->XCD
// pinning (FETCH 77->40MB); CSR build removed (done once in csr_kernel).
// LDS ~1KB -> 4 blocks/CU wave-limited. 2 lanes per row, 16B/lane.
// ---------------------------------------------------------------------------
__global__ __launch_bounds__(512) void accumulate_kernel(const unsigned short* __restrict__ hb,
                                                         const int* __restrict__ gsrt,
                                                         const int* __restrict__ gstart,
                                                         const float* __restrict__ bias,
                                                         float* __restrict__ out) {
    __shared__ int start[G + 1];

    const int blk = blockIdx.x;
    const int b   = blk >> 2;                    // bucket
    const int s   = blk & 3;                     // feature plane (16 feats)
    const int tid = threadIdx.x;

    if (tid <= G) start[tid] = gstart[b * 256 + tid];
    __syncthreads();

    const int r    = tid >> 1;                   // row 0..255 (>=240 idle)
    const int half = tid & 1;
    const unsigned short* hp = hb + (size_t)s * PLANE_STRIDE;
    const int* srt = gsrt + (size_t)b * CAP;

    if (r < G) {
        const int node = b * G + r;
        const int st = start[r];
        const int en = start[r + 1];
        float acc[16];
        #pragma unroll
        for (int k = 0; k < 16; ++k) acc[k] = 0.f;

        int j = st + half;
        for (; j + 2 < en; j += 4) {             // 2 edges per lane per iter
            const int s0 = srt[j], s1 = srt[j + 2];
            const us16x8 a0 = *reinterpret_cast<const us16x8*>(hp + (size_t)s0 * 16);
            const us16x8 a1 = *reinterpret_cast<const us16x8*>(hp + (size_t)s0 * 16 + 8);
            const us16x8 c0 = *reinterpret_cast<const us16x8*>(hp + (size_t)s1 * 16);
            const us16x8 c1 = *reinterpret_cast<const us16x8*>(hp + (size_t)s1 * 16 + 8);
            #pragma unroll
            for (int k = 0; k < 8; ++k) {
                acc[k]     += bf2f(a0[k]) + bf2f(c0[k]);
                acc[8 + k] += bf2f(a1[k]) + bf2f(c1[k]);
            }
        }
        for (; j < en; j += 2) {
            const int s0 = srt[j];
            const us16x8 a0 = *reinterpret_cast<const us16x8*>(hp + (size_t)s0 * 16);
            const us16x8 a1 = *reinterpret_cast<const us16x8*>(hp + (size_t)s0 * 16 + 8);
            #pragma unroll
            for (int k = 0; k < 8; ++k) {
                acc[k]     += bf2f(a0[k]);
                acc[8 + k] += bf2f(a1[k]);
            }
        }

        // pair combine: lane h keeps feats [8h,8h+8)
        float tot[8];
        #pragma unroll
        for (int k = 0; k < 8; ++k) {
            const float send = acc[((half ^ 1) << 3) + k];
            const float recv = __shfl_xor(send, 1, 64);
            tot[k] = acc[(half << 3) + k] + recv;
        }

        if (node < N_NODES) {
            const float* bp = bias + s * 16 + half * 8;
            float4 o0, o1;
            o0.x = fmaxf(tot[0] + bp[0], 0.f);
            o0.y = fmaxf(tot[1] + bp[1], 0.f);
            o0.z = fmaxf(tot[2] + bp[2], 0.f);
            o0.w = fmaxf(tot[3] + bp[3], 0.f);
            o1.x = fmaxf(tot[4] + bp[4], 0.f);
            o1.y = fmaxf(tot[5] + bp[5], 0.f);
            o1.z = fmaxf(tot[6] + bp[6], 0.f);
            o1.w = fmaxf(tot[7] + bp[7], 0.f);
            float4* op = reinterpret_cast<float4*>(out + (size_t)node * D_OUT + s * 16 + half * 8);
            op[0] = o0;
            op[1] = o1;
        }
    }

    if (tid == 0) spin_pad_20us();   // DIAGNOSTIC pad (accumulate only)
}

// ---------------------------------------------------------------------------
// Fallback path (standalone gemm + atomic scatter) if ws too small
// ---------------------------------------------------------------------------
__global__ __launch_bounds__(256) void gemm_fallback_kernel(const float* __restrict__ x,
                                                            const float* __restrict__ W,
                                                            unsigned short* __restrict__ hb) {
    __shared__ unsigned short Wt[D_OUT * WSTR];
    const int tid = threadIdx.x;
    for (int i = tid; i < D_IN * D_OUT; i += 256) {
        const int k = i >> 6;
        const int f = i & 63;
        Wt[f * WSTR + k] = f2bf(W[i]);
    }
    __syncthreads();

    const int wave = tid >> 6;
    const int lane = tid & 63;
    const int m    = lane & 15;
    const int quad = lane >> 4;
    const int n0   = blockIdx.x * 64 + wave * 16;

    bf16x8 bfrag[4][4];
    #pragma unroll
    for (int ft = 0; ft < 4; ++ft)
        #pragma unroll
        for (int ks = 0; ks < 4; ++ks)
            bfrag[ft][ks] = *reinterpret_cast<const bf16x8*>(
                &Wt[(ft * 16 + m) * WSTR + ks * 32 + quad * 8]);

    const int nodeA = min(n0 + m, N_NODES - 1);
    const float* xr = x + (size_t)nodeA * D_IN;
    bf16x8 afrag[4];
    #pragma unroll
    for (int ks = 0; ks < 4; ++ks) {
        const float4 u = *reinterpret_cast<const float4*>(xr + ks * 32 + quad * 8);
        const float4 v = *reinterpret_cast<const float4*>(xr + ks * 32 + quad * 8 + 4);
        bf16x8 a;
        a[0] = (short)f2bf(u.x); a[1] = (short)f2bf(u.y);
        a[2] = (short)f2bf(u.z); a[3] = (short)f2bf(u.w);
        a[4] = (short)f2bf(v.x); a[5] = (short)f2bf(v.y);
        a[6] = (short)f2bf(v.z); a[7] = (short)f2bf(v.w);
        afrag[ks] = a;
    }

    f32x4 acc[4];
    #pragma unroll
    for (int ft = 0; ft < 4; ++ft) { acc[ft][0]=0.f; acc[ft][1]=0.f; acc[ft][2]=0.f; acc[ft][3]=0.f; }

    #pragma unroll
    for (int ks = 0; ks < 4; ++ks)
        #pragma unroll
        for (int ft = 0; ft < 4; ++ft)
            acc[ft] = __builtin_amdgcn_mfma_f32_16x16x32_bf16(
                afrag[ks], bfrag[ft][ks], acc[ft], 0, 0, 0);

    #pragma unroll
    for (int r = 0; r < 4; ++r) {
        const int node = n0 + quad * 4 + r;
        if (node < N_NODES) {
            #pragma unroll
            for (int ft = 0; ft < 4; ++ft)
                hb[ft * PLANE_STRIDE + (size_t)node * 16 + m] = f2bf(acc[ft][r]);
        }
    }
}

__global__ void init_bias_kernel(float* __restrict__ out, const float* __restrict__ b) {
    int i = blockIdx.x * blockDim.x + threadIdx.x;
    const int total4 = N_NODES * (D_OUT / 4);
    if (i < total4) {
        int f4 = i & (D_OUT / 4 - 1);
        reinterpret_cast<float4*>(out)[i] = reinterpret_cast<const float4*>(b)[f4];
    }
}

__global__ void scatter_kernel(const unsigned short* __restrict__ hb, const int* __restrict__ ei,
                               float* __restrict__ out) {
    const long long t = (long long)blockIdx.x * blockDim.x + threadIdx.x;
    const int e = (int)(t >> 6);
    const int f = (int)(t & 63);
    if (e < N_EDGES) {
        const int src = ei[e];
        atomicAdd(out + (size_t)ei[N_EDGES + e] * D_OUT + f,
                  bf2f(hb[(f >> 4) * PLANE_STRIDE + (size_t)src * 16 + (f & 15)]));
    }
}

__global__ void relu_kernel(float* __restrict__ out) {
    int i = blockIdx.x * blockDim.x + threadIdx.x;
    const int total4 = N_NODES * (D_OUT / 4);
    if (i < total4) {
        float4 v = reinterpret_cast<float4*>(out)[i];
        v.x = fmaxf(v.x, 0.f); v.y = fmaxf(v.y, 0.f);
        v.z = fmaxf(v.z, 0.f); v.w = fmaxf(v.w, 0.f);
        reinterpret_cast<float4*>(out)[i] = v;
    }
}

// ---------------------------------------------------------------------------
extern "C" void kernel_launch(void* const* d_in, const int* in_sizes, int n_in,
                              void* d_out, int out_size, void* d_ws, size_t ws_size,
                              hipStream_t stream) {
    const float* x  = (const float*)d_in[0];
    const int*   ei = (const int*)d_in[1];
    const float* W  = (const float*)d_in[2];
    const float* b  = (const float*)d_in[3];
    float* out = (float*)d_out;
    char*  ws  = (char*)d_ws;

    size_t off = 0;
    auto take = [&](size_t bytes) { size_t p = off; off = (off + bytes + 255) & ~255ULL; return p; };
    const size_t o_h     = take((size_t)N_NODES * D_OUT * sizeof(unsigned short)); // 12.8 MB
    const size_t o_gcur  = take((size_t)NBKT * sizeof(int));
    const size_t o_ebuf  = take((size_t)NBKT * CAP * sizeof(int));                 // 10.25 MB
    const size_t o_gsrt  = take((size_t)NBKT * CAP * sizeof(int));                 // 10.25 MB
    const size_t o_gstart= take((size_t)NBKT * 256 * sizeof(int));                 // 0.43 MB
    const size_t needed = off;

    unsigned short* hb = (unsigned short*)(ws + o_h);

    if (needed <= ws_size) {
        int* gcur   = (int*)(ws + o_gcur);
        int* ebuf   = (int*)(ws + o_ebuf);
        int* gsrt   = (int*)(ws + o_gsrt);
        int* gstart = (int*)(ws + o_gstart);
        hipMemsetAsync(gcur, 0, (size_t)NBKT * sizeof(int), stream);
        fused_gp_kernel<<<PBLK + GBLK, 512, 0, stream>>>(x, W, hb, ei, gcur, ebuf);
        csr_kernel<<<NBKT, 512, 0, stream>>>(gcur, ebuf, gsrt, gstart);
        accumulate_kernel<<<NBKT * NPLANE, 512, 0, stream>>>(hb, gsrt, gstart, b, out);
    } else {
        gemm_fallback_kernel<<<(N_NODES + 63) / 64, 256, 0, stream>>>(x, W, hb);
        const int total4 = N_NODES * (D_OUT / 4);
        init_bias_kernel<<<(total4 + 255) / 256, 256, 0, stream>>>(out, b);
        const long long threads = (long long)N_EDGES * 64;
        scatter_kernel<<<(int)((threads + 255) / 256), 256, 0, stream>>>(hb, ei, out);
        relu_kernel<<<(total4 + 255) / 256, 256, 0, stream>>>(out);
    }
}

// Round 7
// 150.532 us; speedup vs baseline: 1.3875x; 1.3875x over previous
//
#include <hip/hip_runtime.h>

#define N_NODES 100000
#define N_EDGES 1600000
#define D_IN    128
#define D_OUT   64

// Bucket scheme: nodes grouped into buckets of G; per-bucket edge lists with
// fixed capacity CAP (avg fill 3840, binomial sd ~62 -> 6144 is ~37 sigma).
#define G     240
#define NBKT  ((N_NODES + G - 1) / G)          // 417
#define CAP   6144
// EPB 8192->4096 (round 7): partition LDS 55.3KB -> 30.7KB => 4 blocks/CU
// (was 2). gp grid 1173 at full occupancy, ~1.15 rounds (was ~1.9).
#define EPB   4096                              // edges per partition block
#define PBLK  ((N_EDGES + EPB - 1) / EPB)       // 391
#define GBLK  ((N_NODES + 127) / 128)           // 782 gemm blocks (128 nodes ea)

// Wt LDS row stride (shorts): 136 = 4 mod 32 banks -> conflict-minimal b128
#define WSTR  136

typedef __attribute__((ext_vector_type(8))) short bf16x8;
typedef __attribute__((ext_vector_type(4))) float f32x4;
typedef __attribute__((ext_vector_type(8))) unsigned short us16x8;

// fp32 <-> bf16 helpers (RNE)
__device__ __forceinline__ unsigned short f2bf(float f) {
    union { float f; unsigned u; } v; v.f = f;
    const unsigned r = v.u + 0x7FFFu + ((v.u >> 16) & 1u);
    return (unsigned short)(r >> 16);
}
__device__ __forceinline__ float bf2f(unsigned short s) {
    union { unsigned u; float f; } v; v.u = ((unsigned)s) << 16;
    return v.f;
}
__device__ __forceinline__ unsigned cvt_pk_bf16(float lo, float hi) {
    unsigned r;
    asm volatile("v_cvt_pk_bf16_f32 %0, %1, %2" : "=v"(r) : "v"(lo), "v"(hi));
    return r;
}

// ---------------------------------------------------------------------------
// Fused gemm + partition. Blocks [0,PBLK): partition EPB=4096 edges each.
// Blocks [PBLK,PBLK+GBLK): bf16 MFMA gemm, 8 waves x 16 nodes.
// hb is node-major [node][64] bf16 (v7 layout -- plane split was a measured
// regression, R5/R6: 32us -> 48us real).
// ---------------------------------------------------------------------------
__global__ __launch_bounds__(512) void fused_gp_kernel(const float* __restrict__ x,
                                                       const float* __restrict__ W,
                                                       unsigned short* __restrict__ hb,
                                                       const int* __restrict__ ei,
                                                       int* __restrict__ gcur,
                                                       int* __restrict__ ebuf) {
    __shared__ int smem[1536 + EPB + EPB / 2];   // 30720 B -> 4 blocks/CU

    const int tid = threadIdx.x;

    if (blockIdx.x < PBLK) {
        // ----------------- partition path -----------------------------------
        int* cnt   = smem;            // [512]
        int* sA    = smem + 512;      // [512] inclusive scan
        int* gbase = smem + 1024;     // [512] adjusted global base (first 8: wave sums)
        int* stage = smem + 1536;     // [EPB] packed edges, bucket-grouped
        unsigned short* bstage = (unsigned short*)(smem + 1536 + EPB); // [EPB]

        cnt[tid] = 0;
        __syncthreads();

        const int e0   = blockIdx.x * EPB;
        const int ecnt = min(EPB, N_EDGES - e0);

        int pk[8], meta[8];
        #pragma unroll
        for (int i = 0; i < 8; ++i) {            // 8*512 = 4096 = EPB
            const int l = tid + i * 512;
            meta[i] = -1;
            if (l < ecnt) {
                const int e   = e0 + l;
                const int src = ei[e];
                const int dst = ei[N_EDGES + e];
                const int b   = dst / G;
                const int dl  = dst - b * G;
                pk[i] = src | (dl << 17);
                const int r = atomicAdd(&cnt[b], 1);   // LDS atomic
                meta[i] = b | (r << 9);                // b:9b, r<4096:12b
            }
        }
        __syncthreads();

        // wave-level inclusive scan of cnt[0..511] (2 barriers)
        {
            const int wv = tid >> 6, ln = tid & 63;
            int s = cnt[tid];
            #pragma unroll
            for (int off = 1; off < 64; off <<= 1) {
                const int t = __shfl_up(s, off, 64);
                if (ln >= off) s += t;
            }
            if (ln == 63) gbase[wv] = s;        // wave totals (gbase[0..7] temp)
            __syncthreads();
            int wbase = 0;
            #pragma unroll
            for (int w = 0; w < 8; ++w) wbase += (w < wv) ? gbase[w] : 0;
            sA[tid] = s + wbase;
            __syncthreads();
        }

        if (tid < NBKT) {
            const int c  = cnt[tid];
            const int ex = sA[tid] - c;
            if (c > 0) gbase[tid] = atomicAdd(&gcur[tid], c) - ex;
        }
        __syncthreads();

        #pragma unroll
        for (int i = 0; i < 8; ++i) {
            if (meta[i] >= 0) {
                const int b    = meta[i] & 511;
                const int r    = meta[i] >> 9;
                const int spos = (sA[b] - cnt[b]) + r;
                stage[spos]  = pk[i];
                bstage[spos] = (unsigned short)b;
            }
        }
        __syncthreads();

        #pragma unroll
        for (int i = 0; i < 8; ++i) {
            const int idx = tid + i * 512;
            if (idx < ecnt) {
                const int b   = bstage[idx];
                const int pib = gbase[b] + idx;     // position in bucket
                if ((unsigned)pib < CAP) ebuf[b * CAP + pib] = stage[idx];
            }
        }
    } else {
        // ----------------- gemm path (bf16 MFMA, padded W^T in LDS) ---------
        unsigned short* Wt = reinterpret_cast<unsigned short*>(smem);
        for (int i = tid; i < (D_IN / 2) * D_OUT; i += 512) {
            const int f  = i & 63;
            const int k2 = (i >> 6) * 2;
            const float w0 = W[k2 * 64 + f];
            const float w1 = W[(k2 + 1) * 64 + f];
            *reinterpret_cast<unsigned*>(&Wt[f * WSTR + k2]) = cvt_pk_bf16(w0, w1);
        }
        __syncthreads();

        const int wave = tid >> 6;                     // 0..7
        const int lane = tid & 63;
        const int m    = lane & 15;
        const int quad = lane >> 4;
        const int n0   = (blockIdx.x - PBLK) * 128 + wave * 16;

        bf16x8 bfrag[4][4];
        #pragma unroll
        for (int ft = 0; ft < 4; ++ft)
            #pragma unroll
            for (int ks = 0; ks < 4; ++ks)
                bfrag[ft][ks] = *reinterpret_cast<const bf16x8*>(
                    &Wt[(ft * 16 + m) * WSTR + ks * 32 + quad * 8]);

        const int nodeA = min(n0 + m, N_NODES - 1);
        const float* xr = x + (size_t)nodeA * D_IN;
        bf16x8 afrag[4];
        #pragma unroll
        for (int ks = 0; ks < 4; ++ks) {
            const float4 u = *reinterpret_cast<const float4*>(xr + ks * 32 + quad * 8);
            const float4 v = *reinterpret_cast<const float4*>(xr + ks * 32 + quad * 8 + 4);
            union { unsigned u32[4]; bf16x8 v8; } c;
            c.u32[0] = cvt_pk_bf16(u.x, u.y);
            c.u32[1] = cvt_pk_bf16(u.z, u.w);
            c.u32[2] = cvt_pk_bf16(v.x, v.y);
            c.u32[3] = cvt_pk_bf16(v.z, v.w);
            afrag[ks] = c.v8;
        }

        f32x4 acc[4];
        #pragma unroll
        for (int ft = 0; ft < 4; ++ft) { acc[ft][0]=0.f; acc[ft][1]=0.f; acc[ft][2]=0.f; acc[ft][3]=0.f; }

        #pragma unroll
        for (int ks = 0; ks < 4; ++ks)
            #pragma unroll
            for (int ft = 0; ft < 4; ++ft)
                acc[ft] = __builtin_amdgcn_mfma_f32_16x16x32_bf16(
                    afrag[ks], bfrag[ft][ks], acc[ft], 0, 0, 0);

        // node-major epilogue: hb[node][ft*16+m]
        #pragma unroll
        for (int r = 0; r < 4; ++r) {
            const int node = n0 + quad * 4 + r;
            if (node < N_NODES) {
                #pragma unroll
                for (int ft = 0; ft < 4; ++ft)
                    hb[(size_t)node * D_OUT + ft * 16 + m] = f2bf(acc[ft][r]);
            }
        }
    }
}

// ---------------------------------------------------------------------------
// Accumulate v7 (revert to R3 config -- best measured: 32us real).
// One 1024-thread block per bucket: CSR build in LDS (atomics + wave scan),
// then one row per 8-lane sub, ushort8 (16B) gathers = 128B/edge in one go.
// The 32us is structural: ~77MB of random HBM/fabric line traffic at the
// measured ~2.4 TB/s random-line rate. Plane-split alternatives measured
// slower (R5/R6: 48us).
// ---------------------------------------------------------------------------
__global__ __launch_bounds__(1024) void accumulate_kernel(const unsigned short* __restrict__ hb,
                                                          const int* __restrict__ gcur,
                                                          const int* __restrict__ ebuf,
                                                          const float* __restrict__ bias,
                                                          float* __restrict__ out) {
    __shared__ int srt[CAP];        // 24 KB
    __shared__ int cnt[256];
    __shared__ int start[G + 1];

    const int b   = blockIdx.x;
    const int tid = threadIdx.x;
    const int ecnt = min(gcur[b], CAP);

    if (tid < 256) cnt[tid] = 0;
    __syncthreads();

    int pk[6], rr[6];
    #pragma unroll
    for (int i = 0; i < 6; ++i) {               // 6*1024 = 6144 = CAP
        const int idx = tid + i * 1024;
        rr[i] = -1;
        if (idx < ecnt) {
            pk[i] = ebuf[(size_t)b * CAP + idx];
            rr[i] = atomicAdd(&cnt[pk[i] >> 17], 1);
        }
    }
    __syncthreads();

    // single-wave exclusive scan of cnt[0..239] -> start[0..240]
    if (tid < 64) {
        int v[4]; int sum = 0;
        #pragma unroll
        for (int k = 0; k < 4; ++k) {
            const int idx = tid * 4 + k;
            v[k] = (idx < G) ? cnt[idx] : 0;
            sum += v[k];
        }
        const int mine = sum;
        for (int off = 1; off < 64; off <<= 1) {
            const int t = __shfl_up(sum, off, 64);
            if (tid >= off) sum += t;
        }
        int base = sum - mine;                   // exclusive prefix at tid*4
        #pragma unroll
        for (int k = 0; k < 4; ++k) {
            const int idx = tid * 4 + k;
            if (idx <= G) start[idx] = base;
            base += v[k];
        }
        if (tid == 63) start[G] = base;
    }
    __syncthreads();

    #pragma unroll
    for (int i = 0; i < 6; ++i) {
        if (rr[i] >= 0) {
            const int dl = pk[i] >> 17;
            srt[start[dl] + rr[i]] = pk[i] & 0x1FFFF;
        }
    }
    __syncthreads();

    // ---- gather: one row per 8-lane sub, 16B/lane (full 128B row / sub) ----
    const int subg = tid >> 3;                   // 0..127 global sub id
    const int f8   = tid & 7;                    // feature octet 0..7
    const us16x8* h8 = reinterpret_cast<const us16x8*>(hb);   // 16B elems, 8/row
    const float* bp = bias + f8 * 8;
    const float4 b0 = *reinterpret_cast<const float4*>(bp);
    const float4 b1 = *reinterpret_cast<const float4*>(bp + 4);

    for (int r = subg; r < G; r += 128) {
        const int node = b * G + r;
        const int s = start[r];
        const int e = start[r + 1];
        float acc[8];
        #pragma unroll
        for (int k = 0; k < 8; ++k) acc[k] = 0.f;

        int j = s;
        for (; j + 3 < e; j += 4) {
            const int s0 = srt[j], s1 = srt[j + 1], s2 = srt[j + 2], s3 = srt[j + 3];
            const us16x8 a0 = h8[(size_t)s0 * 8 + f8];
            const us16x8 a1 = h8[(size_t)s1 * 8 + f8];
            const us16x8 a2 = h8[(size_t)s2 * 8 + f8];
            const us16x8 a3 = h8[(size_t)s3 * 8 + f8];
            #pragma unroll
            for (int k = 0; k < 8; ++k)
                acc[k] += (bf2f(a0[k]) + bf2f(a1[k])) + (bf2f(a2[k]) + bf2f(a3[k]));
        }
        for (; j < e; ++j) {
            const us16x8 a = h8[(size_t)srt[j] * 8 + f8];
            #pragma unroll
            for (int k = 0; k < 8; ++k) acc[k] += bf2f(a[k]);
        }

        if (node < N_NODES) {
            float4 o0, o1;
            o0.x = fmaxf(acc[0] + b0.x, 0.f);
            o0.y = fmaxf(acc[1] + b0.y, 0.f);
            o0.z = fmaxf(acc[2] + b0.z, 0.f);
            o0.w = fmaxf(acc[3] + b0.w, 0.f);
            o1.x = fmaxf(acc[4] + b1.x, 0.f);
            o1.y = fmaxf(acc[5] + b1.y, 0.f);
            o1.z = fmaxf(acc[6] + b1.z, 0.f);
            o1.w = fmaxf(acc[7] + b1.w, 0.f);
            float4* op = reinterpret_cast<float4*>(out + (size_t)node * D_OUT + f8 * 8);
            op[0] = o0;
            op[1] = o1;
        }
    }
}

// ---------------------------------------------------------------------------
// Fallback path (standalone gemm + atomic scatter) if ws too small
// ---------------------------------------------------------------------------
__global__ __launch_bounds__(256) void gemm_fallback_kernel(const float* __restrict__ x,
                                                            const float* __restrict__ W,
                                                            unsigned short* __restrict__ hb) {
    __shared__ unsigned short Wt[D_OUT * WSTR];
    const int tid = threadIdx.x;
    for (int i = tid; i < D_IN * D_OUT; i += 256) {
        const int k = i >> 6;
        const int f = i & 63;
        Wt[f * WSTR + k] = f2bf(W[i]);
    }
    __syncthreads();

    const int wave = tid >> 6;
    const int lane = tid & 63;
    const int m    = lane & 15;
    const int quad = lane >> 4;
    const int n0   = blockIdx.x * 64 + wave * 16;

    bf16x8 bfrag[4][4];
    #pragma unroll
    for (int ft = 0; ft < 4; ++ft)
        #pragma unroll
        for (int ks = 0; ks < 4; ++ks)
            bfrag[ft][ks] = *reinterpret_cast<const bf16x8*>(
                &Wt[(ft * 16 + m) * WSTR + ks * 32 + quad * 8]);

    const int nodeA = min(n0 + m, N_NODES - 1);
    const float* xr = x + (size_t)nodeA * D_IN;
    bf16x8 afrag[4];
    #pragma unroll
    for (int ks = 0; ks < 4; ++ks) {
        const float4 u = *reinterpret_cast<const float4*>(xr + ks * 32 + quad * 8);
        const float4 v = *reinterpret_cast<const float4*>(xr + ks * 32 + quad * 8 + 4);
        bf16x8 a;
        a[0] = (short)f2bf(u.x); a[1] = (short)f2bf(u.y);
        a[2] = (short)f2bf(u.z); a[3] = (short)f2bf(u.w);
        a[4] = (short)f2bf(v.x); a[5] = (short)f2bf(v.y);
        a[6] = (short)f2bf(v.z); a[7] = (short)f2bf(v.w);
        afrag[ks] = a;
    }

    f32x4 acc[4];
    #pragma unroll
    for (int ft = 0; ft < 4; ++ft) { acc[ft][0]=0.f; acc[ft][1]=0.f; acc[ft][2]=0.f; acc[ft][3]=0.f; }

    #pragma unroll
    for (int ks = 0; ks < 4; ++ks)
        #pragma unroll
        for (int ft = 0; ft < 4; ++ft)
            acc[ft] = __builtin_amdgcn_mfma_f32_16x16x32_bf16(
                afrag[ks], bfrag[ft][ks], acc[ft], 0, 0, 0);

    #pragma unroll
    for (int r = 0; r < 4; ++r) {
        const int node = n0 + quad * 4 + r;
        if (node < N_NODES) {
            #pragma unroll
            for (int ft = 0; ft < 4; ++ft)
                hb[(size_t)node * D_OUT + ft * 16 + m] = f2bf(acc[ft][r]);
        }
    }
}

__global__ void init_bias_kernel(float* __restrict__ out, const float* __restrict__ b) {
    int i = blockIdx.x * blockDim.x + threadIdx.x;
    const int total4 = N_NODES * (D_OUT / 4);
    if (i < total4) {
        int f4 = i & (D_OUT / 4 - 1);
        reinterpret_cast<float4*>(out)[i] = reinterpret_cast<const float4*>(b)[f4];
    }
}

__global__ void scatter_kernel(const unsigned short* __restrict__ hb, const int* __restrict__ ei,
                               float* __restrict__ out) {
    const long long t = (long long)blockIdx.x * blockDim.x + threadIdx.x;
    const int e = (int)(t >> 6);
    const int f = (int)(t & 63);
    if (e < N_EDGES) {
        atomicAdd(out + (size_t)ei[N_EDGES + e] * D_OUT + f,
                  bf2f(hb[(size_t)ei[e] * D_OUT + f]));
    }
}

__global__ void relu_kernel(float* __restrict__ out) {
    int i = blockIdx.x * blockDim.x + threadIdx.x;
    const int total4 = N_NODES * (D_OUT / 4);
    if (i < total4) {
        float4 v = reinterpret_cast<float4*>(out)[i];
        v.x = fmaxf(v.x, 0.f); v.y = fmaxf(v.y, 0.f);
        v.z = fmaxf(v.z, 0.f); v.w = fmaxf(v.w, 0.f);
        reinterpret_cast<float4*>(out)[i] = v;
    }
}

// ---------------------------------------------------------------------------
extern "C" void kernel_launch(void* const* d_in, const int* in_sizes, int n_in,
                              void* d_out, int out_size, void* d_ws, size_t ws_size,
                              hipStream_t stream) {
    const float* x  = (const float*)d_in[0];
    const int*   ei = (const int*)d_in[1];
    const float* W  = (const float*)d_in[2];
    const float* b  = (const float*)d_in[3];
    float* out = (float*)d_out;
    char*  ws  = (char*)d_ws;

    size_t off = 0;
    auto take = [&](size_t bytes) { size_t p = off; off = (off + bytes + 255) & ~255ULL; return p; };
    const size_t o_h    = take((size_t)N_NODES * D_OUT * sizeof(unsigned short)); // 12.8 MB
    const size_t o_gcur = take((size_t)NBKT * sizeof(int));
    const size_t o_ebuf = take((size_t)NBKT * CAP * sizeof(int));                 // 10.25 MB
    const size_t needed = off;

    unsigned short* hb = (unsigned short*)(ws + o_h);

    if (needed <= ws_size) {
        int* gcur = (int*)(ws + o_gcur);
        int* ebuf = (int*)(ws + o_ebuf);
        hipMemsetAsync(gcur, 0, (size_t)NBKT * sizeof(int), stream);
        fused_gp_kernel<<<PBLK + GBLK, 512, 0, stream>>>(x, W, hb, ei, gcur, ebuf);
        accumulate_kernel<<<NBKT, 1024, 0, stream>>>(hb, gcur, ebuf, b, out);
    } else {
        gemm_fallback_kernel<<<(N_NODES + 63) / 64, 256, 0, stream>>>(x, W, hb);
        const int total4 = N_NODES * (D_OUT / 4);
        init_bias_kernel<<<(total4 + 255) / 256, 256, 0, stream>>>(out, b);
        const long long threads = (long long)N_EDGES * 64;
        scatter_kernel<<<(int)((threads + 255) / 256), 256, 0, stream>>>(hb, ei, out);
        relu_kernel<<<(total4 + 255) / 256, 256, 0, stream>>>(out);
    }
}

// Round 8
// 149.205 us; speedup vs baseline: 1.3999x; 1.0089x over previous
//
#include <hip/hip_runtime.h>

#define N_NODES 100000
#define N_EDGES 1600000
#define D_IN    128
#define D_OUT   64

// Bucket scheme: nodes grouped into buckets of G; per-bucket edge lists with
// fixed capacity CAP (avg fill 3840, binomial sd ~62 -> 6144 is ~37 sigma).
#define G     240
#define NBKT  ((N_NODES + G - 1) / G)          // 417
#define CAP   6144
// EPB = 8192: best measured (R3/R4). EPB=4096 (R7) regressed +6us -- per-block
// fixed costs (512-wide scan, gcur atomic round) doubled with block count.
#define EPB   8192                              // edges per partition block
#define PBLK  ((N_EDGES + EPB - 1) / EPB)       // 196
#define GBLK  ((N_NODES + 127) / 128)           // 782 gemm blocks (128 nodes ea)

// Wt LDS row stride (shorts): 136 = 4 mod 32 banks -> conflict-minimal b128
#define WSTR  136

typedef __attribute__((ext_vector_type(8))) short bf16x8;
typedef __attribute__((ext_vector_type(4))) float f32x4;
typedef __attribute__((ext_vector_type(8))) unsigned short us16x8;

// fp32 <-> bf16 helpers (RNE)
__device__ __forceinline__ unsigned short f2bf(float f) {
    union { float f; unsigned u; } v; v.f = f;
    const unsigned r = v.u + 0x7FFFu + ((v.u >> 16) & 1u);
    return (unsigned short)(r >> 16);
}
__device__ __forceinline__ float bf2f(unsigned short s) {
    union { unsigned u; float f; } v; v.u = ((unsigned)s) << 16;
    return v.f;
}
__device__ __forceinline__ unsigned cvt_pk_bf16(float lo, float hi) {
    unsigned r;
    asm volatile("v_cvt_pk_bf16_f32 %0, %1, %2" : "=v"(r) : "v"(lo), "v"(hi));
    return r;
}

// ---------------------------------------------------------------------------
// Fused gemm + partition (best-measured config: EPB 8192, ~25us real).
// Blocks [0,PBLK): partition. [PBLK,PBLK+GBLK): bf16 MFMA gemm.
// ---------------------------------------------------------------------------
__global__ __launch_bounds__(512) void fused_gp_kernel(const float* __restrict__ x,
                                                       const float* __restrict__ W,
                                                       unsigned short* __restrict__ hb,
                                                       const int* __restrict__ ei,
                                                       int* __restrict__ gcur,
                                                       int* __restrict__ ebuf) {
    __shared__ int smem[1536 + EPB + EPB / 2];   // 55296 B

    const int tid = threadIdx.x;

    if (blockIdx.x < PBLK) {
        // ----------------- partition path -----------------------------------
        int* cnt   = smem;            // [512]
        int* sA    = smem + 512;      // [512] inclusive scan
        int* gbase = smem + 1024;     // [512] adjusted global base (first 8: wave sums)
        int* stage = smem + 1536;     // [EPB] packed edges, bucket-grouped
        unsigned short* bstage = (unsigned short*)(smem + 1536 + EPB); // [EPB]

        cnt[tid] = 0;
        __syncthreads();

        const int e0   = blockIdx.x * EPB;
        const int ecnt = min(EPB, N_EDGES - e0);

        int pk[16], meta[16];
        #pragma unroll
        for (int i = 0; i < 16; ++i) {           // 16*512 = 8192 = EPB
            const int l = tid + i * 512;
            meta[i] = -1;
            if (l < ecnt) {
                const int e   = e0 + l;
                const int src = ei[e];
                const int dst = ei[N_EDGES + e];
                const int b   = dst / G;
                const int dl  = dst - b * G;
                pk[i] = src | (dl << 17);
                const int r = atomicAdd(&cnt[b], 1);   // LDS atomic
                meta[i] = b | (r << 9);                // b:9b, r<8192:13b
            }
        }
        __syncthreads();

        // wave-level inclusive scan of cnt[0..511] (2 barriers)
        {
            const int wv = tid >> 6, ln = tid & 63;
            int s = cnt[tid];
            #pragma unroll
            for (int off = 1; off < 64; off <<= 1) {
                const int t = __shfl_up(s, off, 64);
                if (ln >= off) s += t;
            }
            if (ln == 63) gbase[wv] = s;        // wave totals (gbase[0..7] temp)
            __syncthreads();
            int wbase = 0;
            #pragma unroll
            for (int w = 0; w < 8; ++w) wbase += (w < wv) ? gbase[w] : 0;
            sA[tid] = s + wbase;
            __syncthreads();
        }

        if (tid < NBKT) {
            const int c  = cnt[tid];
            const int ex = sA[tid] - c;
            if (c > 0) gbase[tid] = atomicAdd(&gcur[tid], c) - ex;
        }
        __syncthreads();

        #pragma unroll
        for (int i = 0; i < 16; ++i) {
            if (meta[i] >= 0) {
                const int b    = meta[i] & 511;
                const int r    = meta[i] >> 9;
                const int spos = (sA[b] - cnt[b]) + r;
                stage[spos]  = pk[i];
                bstage[spos] = (unsigned short)b;
            }
        }
        __syncthreads();

        #pragma unroll
        for (int i = 0; i < 16; ++i) {
            const int idx = tid + i * 512;
            if (idx < ecnt) {
                const int b   = bstage[idx];
                const int pib = gbase[b] + idx;     // position in bucket
                if ((unsigned)pib < CAP) ebuf[b * CAP + pib] = stage[idx];
            }
        }
    } else {
        // ----------------- gemm path (bf16 MFMA, padded W^T in LDS) ---------
        unsigned short* Wt = reinterpret_cast<unsigned short*>(smem);
        for (int i = tid; i < (D_IN / 2) * D_OUT; i += 512) {
            const int f  = i & 63;
            const int k2 = (i >> 6) * 2;
            const float w0 = W[k2 * 64 + f];
            const float w1 = W[(k2 + 1) * 64 + f];
            *reinterpret_cast<unsigned*>(&Wt[f * WSTR + k2]) = cvt_pk_bf16(w0, w1);
        }
        __syncthreads();

        const int wave = tid >> 6;                     // 0..7
        const int lane = tid & 63;
        const int m    = lane & 15;
        const int quad = lane >> 4;
        const int n0   = (blockIdx.x - PBLK) * 128 + wave * 16;

        bf16x8 bfrag[4][4];
        #pragma unroll
        for (int ft = 0; ft < 4; ++ft)
            #pragma unroll
            for (int ks = 0; ks < 4; ++ks)
                bfrag[ft][ks] = *reinterpret_cast<const bf16x8*>(
                    &Wt[(ft * 16 + m) * WSTR + ks * 32 + quad * 8]);

        const int nodeA = min(n0 + m, N_NODES - 1);
        const float* xr = x + (size_t)nodeA * D_IN;
        bf16x8 afrag[4];
        #pragma unroll
        for (int ks = 0; ks < 4; ++ks) {
            const float4 u = *reinterpret_cast<const float4*>(xr + ks * 32 + quad * 8);
            const float4 v = *reinterpret_cast<const float4*>(xr + ks * 32 + quad * 8 + 4);
            union { unsigned u32[4]; bf16x8 v8; } c;
            c.u32[0] = cvt_pk_bf16(u.x, u.y);
            c.u32[1] = cvt_pk_bf16(u.z, u.w);
            c.u32[2] = cvt_pk_bf16(v.x, v.y);
            c.u32[3] = cvt_pk_bf16(v.z, v.w);
            afrag[ks] = c.v8;
        }

        f32x4 acc[4];
        #pragma unroll
        for (int ft = 0; ft < 4; ++ft) { acc[ft][0]=0.f; acc[ft][1]=0.f; acc[ft][2]=0.f; acc[ft][3]=0.f; }

        #pragma unroll
        for (int ks = 0; ks < 4; ++ks)
            #pragma unroll
            for (int ft = 0; ft < 4; ++ft)
                acc[ft] = __builtin_amdgcn_mfma_f32_16x16x32_bf16(
                    afrag[ks], bfrag[ft][ks], acc[ft], 0, 0, 0);

        // node-major epilogue: hb[node][ft*16+m]
        #pragma unroll
        for (int r = 0; r < 4; ++r) {
            const int node = n0 + quad * 4 + r;
            if (node < N_NODES) {
                #pragma unroll
                for (int ft = 0; ft < 4; ++ft)
                    hb[(size_t)node * D_OUT + ft * 16 + m] = f2bf(acc[ft][r]);
            }
        }
    }
}

// ---------------------------------------------------------------------------
// Accumulate v7 (best measured: ~32us real). One 1024-thread block per
// bucket: CSR build in LDS (atomics + wave scan), then one row per 8-lane
// sub, ushort8 (16B) gathers = full 128B row per sub per edge.
// Floor is structural: ~77MB of random L2-miss line traffic at the measured
// ~2.4 TB/s random-line rate. Alternatives measured worse: plane-split
// (R5/R6, 48us), wider wave concurrency (R3, neutral).
// ---------------------------------------------------------------------------
__global__ __launch_bounds__(1024) void accumulate_kernel(const unsigned short* __restrict__ hb,
                                                          const int* __restrict__ gcur,
                                                          const int* __restrict__ ebuf,
                                                          const float* __restrict__ bias,
                                                          float* __restrict__ out) {
    __shared__ int srt[CAP];        // 24 KB
    __shared__ int cnt[256];
    __shared__ int start[G + 1];

    const int b   = blockIdx.x;
    const int tid = threadIdx.x;
    const int ecnt = min(gcur[b], CAP);

    if (tid < 256) cnt[tid] = 0;
    __syncthreads();

    int pk[6], rr[6];
    #pragma unroll
    for (int i = 0; i < 6; ++i) {               // 6*1024 = 6144 = CAP
        const int idx = tid + i * 1024;
        rr[i] = -1;
        if (idx < ecnt) {
            pk[i] = ebuf[(size_t)b * CAP + idx];
            rr[i] = atomicAdd(&cnt[pk[i] >> 17], 1);
        }
    }
    __syncthreads();

    // single-wave exclusive scan of cnt[0..239] -> start[0..240]
    if (tid < 64) {
        int v[4]; int sum = 0;
        #pragma unroll
        for (int k = 0; k < 4; ++k) {
            const int idx = tid * 4 + k;
            v[k] = (idx < G) ? cnt[idx] : 0;
            sum += v[k];
        }
        const int mine = sum;
        for (int off = 1; off < 64; off <<= 1) {
            const int t = __shfl_up(sum, off, 64);
            if (tid >= off) sum += t;
        }
        int base = sum - mine;                   // exclusive prefix at tid*4
        #pragma unroll
        for (int k = 0; k < 4; ++k) {
            const int idx = tid * 4 + k;
            if (idx <= G) start[idx] = base;
            base += v[k];
        }
        if (tid == 63) start[G] = base;
    }
    __syncthreads();

    #pragma unroll
    for (int i = 0; i < 6; ++i) {
        if (rr[i] >= 0) {
            const int dl = pk[i] >> 17;
            srt[start[dl] + rr[i]] = pk[i] & 0x1FFFF;
        }
    }
    __syncthreads();

    // ---- gather: one row per 8-lane sub, 16B/lane (full 128B row / sub) ----
    const int subg = tid >> 3;                   // 0..127 global sub id
    const int f8   = tid & 7;                    // feature octet 0..7
    const us16x8* h8 = reinterpret_cast<const us16x8*>(hb);   // 16B elems, 8/row
    const float* bp = bias + f8 * 8;
    const float4 b0 = *reinterpret_cast<const float4*>(bp);
    const float4 b1 = *reinterpret_cast<const float4*>(bp + 4);

    for (int r = subg; r < G; r += 128) {
        const int node = b * G + r;
        const int s = start[r];
        const int e = start[r + 1];
        float acc[8];
        #pragma unroll
        for (int k = 0; k < 8; ++k) acc[k] = 0.f;

        int j = s;
        for (; j + 3 < e; j += 4) {
            const int s0 = srt[j], s1 = srt[j + 1], s2 = srt[j + 2], s3 = srt[j + 3];
            const us16x8 a0 = h8[(size_t)s0 * 8 + f8];
            const us16x8 a1 = h8[(size_t)s1 * 8 + f8];
            const us16x8 a2 = h8[(size_t)s2 * 8 + f8];
            const us16x8 a3 = h8[(size_t)s3 * 8 + f8];
            #pragma unroll
            for (int k = 0; k < 8; ++k)
                acc[k] += (bf2f(a0[k]) + bf2f(a1[k])) + (bf2f(a2[k]) + bf2f(a3[k]));
        }
        for (; j < e; ++j) {
            const us16x8 a = h8[(size_t)srt[j] * 8 + f8];
            #pragma unroll
            for (int k = 0; k < 8; ++k) acc[k] += bf2f(a[k]);
        }

        if (node < N_NODES) {
            float4 o0, o1;
            o0.x = fmaxf(acc[0] + b0.x, 0.f);
            o0.y = fmaxf(acc[1] + b0.y, 0.f);
            o0.z = fmaxf(acc[2] + b0.z, 0.f);
            o0.w = fmaxf(acc[3] + b0.w, 0.f);
            o1.x = fmaxf(acc[4] + b1.x, 0.f);
            o1.y = fmaxf(acc[5] + b1.y, 0.f);
            o1.z = fmaxf(acc[6] + b1.z, 0.f);
            o1.w = fmaxf(acc[7] + b1.w, 0.f);
            float4* op = reinterpret_cast<float4*>(out + (size_t)node * D_OUT + f8 * 8);
            op[0] = o0;
            op[1] = o1;
        }
    }
}

// ---------------------------------------------------------------------------
// Fallback path (standalone gemm + atomic scatter) if ws too small
// ---------------------------------------------------------------------------
__global__ __launch_bounds__(256) void gemm_fallback_kernel(const float* __restrict__ x,
                                                            const float* __restrict__ W,
                                                            unsigned short* __restrict__ hb) {
    __shared__ unsigned short Wt[D_OUT * WSTR];
    const int tid = threadIdx.x;
    for (int i = tid; i < D_IN * D_OUT; i += 256) {
        const int k = i >> 6;
        const int f = i & 63;
        Wt[f * WSTR + k] = f2bf(W[i]);
    }
    __syncthreads();

    const int wave = tid >> 6;
    const int lane = tid & 63;
    const int m    = lane & 15;
    const int quad = lane >> 4;
    const int n0   = blockIdx.x * 64 + wave * 16;

    bf16x8 bfrag[4][4];
    #pragma unroll
    for (int ft = 0; ft < 4; ++ft)
        #pragma unroll
        for (int ks = 0; ks < 4; ++ks)
            bfrag[ft][ks] = *reinterpret_cast<const bf16x8*>(
                &Wt[(ft * 16 + m) * WSTR + ks * 32 + quad * 8]);

    const int nodeA = min(n0 + m, N_NODES - 1);
    const float* xr = x + (size_t)nodeA * D_IN;
    bf16x8 afrag[4];
    #pragma unroll
    for (int ks = 0; ks < 4; ++ks) {
        const float4 u = *reinterpret_cast<const float4*>(xr + ks * 32 + quad * 8);
        const float4 v = *reinterpret_cast<const float4*>(xr + ks * 32 + quad * 8 + 4);
        bf16x8 a;
        a[0] = (short)f2bf(u.x); a[1] = (short)f2bf(u.y);
        a[2] = (short)f2bf(u.z); a[3] = (short)f2bf(u.w);
        a[4] = (short)f2bf(v.x); a[5] = (short)f2bf(v.y);
        a[6] = (short)f2bf(v.z); a[7] = (short)f2bf(v.w);
        afrag[ks] = a;
    }

    f32x4 acc[4];
    #pragma unroll
    for (int ft = 0; ft < 4; ++ft) { acc[ft][0]=0.f; acc[ft][1]=0.f; acc[ft][2]=0.f; acc[ft][3]=0.f; }

    #pragma unroll
    for (int ks = 0; ks < 4; ++ks)
        #pragma unroll
        for (int ft = 0; ft < 4; ++ft)
            acc[ft] = __builtin_amdgcn_mfma_f32_16x16x32_bf16(
                afrag[ks], bfrag[ft][ks], acc[ft], 0, 0, 0);

    #pragma unroll
    for (int r = 0; r < 4; ++r) {
        const int node = n0 + quad * 4 + r;
        if (node < N_NODES) {
            #pragma unroll
            for (int ft = 0; ft < 4; ++ft)
                hb[(size_t)node * D_OUT + ft * 16 + m] = f2bf(acc[ft][r]);
        }
    }
}

__global__ void init_bias_kernel(float* __restrict__ out, const float* __restrict__ b) {
    int i = blockIdx.x * blockDim.x + threadIdx.x;
    const int total4 = N_NODES * (D_OUT / 4);
    if (i < total4) {
        int f4 = i & (D_OUT / 4 - 1);
        reinterpret_cast<float4*>(out)[i] = reinterpret_cast<const float4*>(b)[f4];
    }
}

__global__ void scatter_kernel(const unsigned short* __restrict__ hb, const int* __restrict__ ei,
                               float* __restrict__ out) {
    const long long t = (long long)blockIdx.x * blockDim.x + threadIdx.x;
    const int e = (int)(t >> 6);
    const int f = (int)(t & 63);
    if (e < N_EDGES) {
        atomicAdd(out + (size_t)ei[N_EDGES + e] * D_OUT + f,
                  bf2f(hb[(size_t)ei[e] * D_OUT + f]));
    }
}

__global__ void relu_kernel(float* __restrict__ out) {
    int i = blockIdx.x * blockDim.x + threadIdx.x;
    const int total4 = N_NODES * (D_OUT / 4);
    if (i < total4) {
        float4 v = reinterpret_cast<float4*>(out)[i];
        v.x = fmaxf(v.x, 0.f); v.y = fmaxf(v.y, 0.f);
        v.z = fmaxf(v.z, 0.f); v.w = fmaxf(v.w, 0.f);
        reinterpret_cast<float4*>(out)[i] = v;
    }
}

// ---------------------------------------------------------------------------
extern "C" void kernel_launch(void* const* d_in, const int* in_sizes, int n_in,
                              void* d_out, int out_size, void* d_ws, size_t ws_size,
                              hipStream_t stream) {
    const float* x  = (const float*)d_in[0];
    const int*   ei = (const int*)d_in[1];
    const float* W  = (const float*)d_in[2];
    const float* b  = (const float*)d_in[3];
    float* out = (float*)d_out;
    char*  ws  = (char*)d_ws;

    size_t off = 0;
    auto take = [&](size_t bytes) { size_t p = off; off = (off + bytes + 255) & ~255ULL; return p; };
    const size_t o_h    = take((size_t)N_NODES * D_OUT * sizeof(unsigned short)); // 12.8 MB
    const size_t o_gcur = take((size_t)NBKT * sizeof(int));
    const size_t o_ebuf = take((size_t)NBKT * CAP * sizeof(int));                 // 10.25 MB
    const size_t needed = off;

    unsigned short* hb = (unsigned short*)(ws + o_h);

    if (needed <= ws_size) {
        int* gcur = (int*)(ws + o_gcur);
        int* ebuf = (int*)(ws + o_ebuf);
        hipMemsetAsync(gcur, 0, (size_t)NBKT * sizeof(int), stream);
        fused_gp_kernel<<<PBLK + GBLK, 512, 0, stream>>>(x, W, hb, ei, gcur, ebuf);
        accumulate_kernel<<<NBKT, 1024, 0, stream>>>(hb, gcur, ebuf, b, out);
    } else {
        gemm_fallback_kernel<<<(N_NODES + 63) / 64, 256, 0, stream>>>(x, W, hb);
        const int total4 = N_NODES * (D_OUT / 4);
        init_bias_kernel<<<(total4 + 255) / 256, 256, 0, stream>>>(out, b);
        const long long threads = (long long)N_EDGES * 64;
        scatter_kernel<<<(int)((threads + 255) / 256), 256, 0, stream>>>(hb, ei, out);
        relu_kernel<<<(total4 + 255) / 256, 256, 0, stream>>>(out);
    }
}